// Round 2
// baseline (699.315 us; speedup 1.0000x reference)
//
#include <hip/hip_runtime.h>
#include <hip/hip_bf16.h>

typedef short short8 __attribute__((ext_vector_type(8)));
typedef float f32x4 __attribute__((ext_vector_type(4)));

using bf16 = __hip_bfloat16;

#define MFMA16(a, b, c) __builtin_amdgcn_mfma_f32_16x16x32_bf16((a), (b), (c), 0, 0, 0)

__device__ __forceinline__ short8 ldb8(const bf16* p) {
    return *reinterpret_cast<const short8*>(p);
}

// -------------------------------------------------------------------------
// Cast f32 -> bf16 (for w_proj only; all IF-feeding math stays f32/exact).
// -------------------------------------------------------------------------
__global__ __launch_bounds__(256) void k_cast(const float* __restrict__ src,
                                              bf16* __restrict__ dst, int n)
{
    for (int i = blockIdx.x * 256 + threadIdx.x; i < n; i += gridDim.x * 256)
        dst[i] = __float2bfloat16(src[i]);
}

// -------------------------------------------------------------------------
// Kernel 1: QKV projection in FULL F32 (IF discontinuity demands f32 accuracy)
// 64x64 tile, K-step 16, 4x4 per thread. IF epilogue writes bf16 spike tensors:
//   Q2[bh,n,0:64]=qa0+sq  Q2[bh,n,64:128]=sq
//   K2[bh,m,0:64]=sk      K2[bh,m,64:128]=ka0
//   VsT[bh,d,n]=sv        VaT[bh,d,n]=va0   (transposed for PV B-frags)
// All epilogue values are small ints -> bf16-exact.
// -------------------------------------------------------------------------
__global__ __launch_bounds__(256) void k_qkv_f32(
    const float* __restrict__ X, const float* __restrict__ W, const float* __restrict__ bq,
    const float* __restrict__ qvm, const float* __restrict__ kvm, const float* __restrict__ vvm,
    const int* __restrict__ qac, const int* __restrict__ kac, const int* __restrict__ vac,
    bf16* __restrict__ Q2, bf16* __restrict__ K2c, bf16* __restrict__ VsT, bf16* __restrict__ VaT)
{
    __shared__ float As[16][68];   // +4 pad keeps float4 alignment, rotates banks
    __shared__ float Bs[16][68];
    const int tid = threadIdx.x;
    const int r0 = blockIdx.y * 64;          // rows (b*N+n)
    const int c0 = blockIdx.x * 64;          // cols (0..1535)
    const int lr = tid & 63, lk4 = (tid >> 6) * 4;
    const int tm = (tid & 15) * 4, tn = (tid >> 4) * 4;

    float acc[4][4] = {};
    for (int kk = 0; kk < 512; kk += 16) {
        const float4 a4 = *reinterpret_cast<const float4*>(X + (size_t)(r0 + lr) * 512 + kk + lk4);
        const float4 b4 = *reinterpret_cast<const float4*>(W + (size_t)(c0 + lr) * 512 + kk + lk4);
        __syncthreads();
        As[lk4 + 0][lr] = a4.x; As[lk4 + 1][lr] = a4.y; As[lk4 + 2][lr] = a4.z; As[lk4 + 3][lr] = a4.w;
        Bs[lk4 + 0][lr] = b4.x; Bs[lk4 + 1][lr] = b4.y; Bs[lk4 + 2][lr] = b4.z; Bs[lk4 + 3][lr] = b4.w;
        __syncthreads();
        #pragma unroll
        for (int k = 0; k < 16; ++k) {
            const float4 av = *reinterpret_cast<const float4*>(&As[k][tm]);
            const float4 bv = *reinterpret_cast<const float4*>(&Bs[k][tn]);
            const float ar[4] = {av.x, av.y, av.z, av.w};
            const float br[4] = {bv.x, bv.y, bv.z, bv.w};
            #pragma unroll
            for (int i = 0; i < 4; ++i)
                #pragma unroll
                for (int j = 0; j < 4; ++j)
                    acc[i][j] += ar[i] * br[j];
        }
    }

    // epilogue: sel/h uniform per block (64-col tile within one 512-col section)
    const int sel = c0 >> 9;
    const int h   = (c0 & 511) >> 6;
    #pragma unroll
    for (int j = 0; j < 4; ++j) {
        const int col = c0 + tn + j;
        const int d = col & 63;
        const float bcol = bq[col];
        #pragma unroll
        for (int i = 0; i < 4; ++i) {
            const int row = r0 + tm + i;           // b*N+n
            const int b = row >> 10, n = row & 1023;
            const int bh = b * 8 + h;
            const size_t i4 = ((size_t)(bh * 1024 + n)) * 64 + d;
            const float val = acc[i][j] + bcol;
            float vm; int a0;
            if (sel == 0)      { vm = qvm[i4]; a0 = qac[i4]; }
            else if (sel == 1) { vm = kvm[i4]; a0 = kac[i4]; }
            else               { vm = vvm[i4]; a0 = vac[i4]; }
            const float v_ = vm + val;
            int sp = ((v_ >= 1.0f) && (a0 < 7)) ? 1 : 0;
            if ((v_ < 0.0f) && (a0 > -8)) sp -= 1;
            if (sel == 0) {
                const size_t qi = ((size_t)(bh * 1024 + n)) * 128 + d;
                Q2[qi]      = __float2bfloat16((float)(a0 + sp));
                Q2[qi + 64] = __float2bfloat16((float)sp);
            } else if (sel == 1) {
                const size_t ki = ((size_t)(bh * 1024 + n)) * 128 + d;
                K2c[ki]      = __float2bfloat16((float)sp);
                K2c[ki + 64] = __float2bfloat16((float)a0);
            } else {
                const size_t vi = ((size_t)(bh * 64 + d)) * 1024 + n;
                VsT[vi] = __float2bfloat16((float)sp);
                VaT[vi] = __float2bfloat16((float)a0);
            }
        }
    }
}

// -------------------------------------------------------------------------
// Kernel 2a (per batch): scores via MFMA over K=128 concat dims (BIT-EXACT:
// integer spikes * 0.125), softmax*7 + attn IF, P1=aa0+sa, P2=sa (bf16 ints).
// -------------------------------------------------------------------------
__global__ __launch_bounds__(256) void k_score(
    const bf16* __restrict__ Q2, const bf16* __restrict__ K2c,
    const float* __restrict__ avm, const int* __restrict__ aac,
    bf16* __restrict__ P1, bf16* __restrict__ P2, int bb)
{
    __shared__ float S[16 * 1024];
    const int w = threadIdx.x >> 6, lane = threadIdx.x & 63;
    const int lo = lane & 15, hi = lane >> 4;
    const int h = blockIdx.y;
    const int bh = bb * 8 + h;
    const int n0 = blockIdx.x * 16;

    const bf16* qb = Q2 + ((size_t)(bh * 1024 + n0 + lo)) * 128 + hi * 8;
    const short8 a0 = ldb8(qb), a1 = ldb8(qb + 32), a2 = ldb8(qb + 64), a3 = ldb8(qb + 96);

    for (int t = 0; t < 16; ++t) {
        const int c0 = w * 256 + t * 16;
        const bf16* kb = K2c + ((size_t)(bh * 1024 + c0 + lo)) * 128 + hi * 8;
        f32x4 acc = {0.f, 0.f, 0.f, 0.f};
        acc = MFMA16(a0, ldb8(kb),      acc);
        acc = MFMA16(a1, ldb8(kb + 32), acc);
        acc = MFMA16(a2, ldb8(kb + 64), acc);
        acc = MFMA16(a3, ldb8(kb + 96), acc);
        #pragma unroll
        for (int r = 0; r < 4; ++r)
            S[(hi * 4 + r) * 1024 + c0 + lo] = 0.125f * acc[r];  // exact
    }
    __syncthreads();

    const int row = threadIdx.x >> 4, l16 = threadIdx.x & 15;
    float* Sr = S + row * 1024;
    float mx = -3.0e38f;
    #pragma unroll 8
    for (int j = 0; j < 64; ++j) mx = fmaxf(mx, Sr[l16 + (j << 4)]);
    mx = fmaxf(mx, __shfl_xor(mx, 1));
    mx = fmaxf(mx, __shfl_xor(mx, 2));
    mx = fmaxf(mx, __shfl_xor(mx, 4));
    mx = fmaxf(mx, __shfl_xor(mx, 8));
    float sum = 0.f;
    #pragma unroll 8
    for (int j = 0; j < 64; ++j) {
        const int c = l16 + (j << 4);
        const float e = expf(Sr[c] - mx);
        Sr[c] = e;
        sum += e;
    }
    sum += __shfl_xor(sum, 1);
    sum += __shfl_xor(sum, 2);
    sum += __shfl_xor(sum, 4);
    sum += __shfl_xor(sum, 8);

    const size_t g0 = ((size_t)bh * 1024 + (n0 + row)) * 1024;
    const size_t p0 = ((size_t)(h * 1024 + n0 + row)) * 1024;
    for (int j = 0; j < 64; ++j) {
        const int c = l16 + (j << 4);
        const float p7 = (Sr[c] / sum) * 7.0f;
        const float v_ = (avm[g0 + c] + 0.2f) + p7;
        const int a0i = aac[g0 + c];
        int sp = ((v_ >= 1.0f) && (a0i < 7)) ? 1 : 0;
        if ((v_ < 0.0f) && (a0i > -8)) sp -= 1;
        P1[p0 + c] = __float2bfloat16((float)(a0i + sp));
        P2[p0 + c] = __float2bfloat16((float)sp);
    }
}

// -------------------------------------------------------------------------
// Kernel 2b (per batch): O = P1@Vs + P2@Va (exact int MFMA), after-attn IF,
// O2 in [B,N,C] layout.
// -------------------------------------------------------------------------
__global__ __launch_bounds__(256) void k_pv(
    const bf16* __restrict__ P1, const bf16* __restrict__ P2,
    const bf16* __restrict__ VsT, const bf16* __restrict__ VaT,
    bf16* __restrict__ O2, int bb)
{
    const int w = threadIdx.x >> 6, lane = threadIdx.x & 63;
    const int lo = lane & 15, hi = lane >> 4;
    const int h = blockIdx.y, bh = bb * 8 + h;
    const int n0 = blockIdx.x * 16, d0 = w * 16;

    const bf16* p1 = P1 + ((size_t)(h * 1024 + n0 + lo)) * 1024 + hi * 8;
    const bf16* p2 = P2 + ((size_t)(h * 1024 + n0 + lo)) * 1024 + hi * 8;
    const bf16* vs = VsT + ((size_t)(bh * 64 + d0 + lo)) * 1024 + hi * 8;
    const bf16* va = VaT + ((size_t)(bh * 64 + d0 + lo)) * 1024 + hi * 8;

    f32x4 acc = {0.f, 0.f, 0.f, 0.f};
    #pragma unroll 4
    for (int kb = 0; kb < 32; ++kb) {
        acc = MFMA16(ldb8(p1 + kb * 32), ldb8(vs + kb * 32), acc);
        acc = MFMA16(ldb8(p2 + kb * 32), ldb8(va + kb * 32), acc);
    }
    #pragma unroll
    for (int r = 0; r < 4; ++r) {
        const int n = n0 + hi * 4 + r;
        const float o = acc[r];                 // exact integer
        const float o2 = (o >= 0.5f ? 1.f : 0.f) - (o < -0.5f ? 1.f : 0.f);
        O2[((size_t)(bb * 1024 + n)) * 512 + h * 64 + d0 + lo] = __float2bfloat16(o2);
    }
}

// -------------------------------------------------------------------------
// Kernel 3: Y = O2 @ Wp^T + b_proj, f32 output. O2 is ±1/0 (bf16-exact);
// Wp bf16 rounding adds ~5e-4 abs err (<< 0.032 tol), no IF after.
// -------------------------------------------------------------------------
__global__ __launch_bounds__(256) void k_proj(
    const bf16* __restrict__ O2, const bf16* __restrict__ W, const float* __restrict__ bias,
    float* __restrict__ Y)
{
    const int w = threadIdx.x >> 6, lane = threadIdx.x & 63;
    const int lo = lane & 15, hi = lane >> 4;
    const int r0 = blockIdx.y * 16;
    const int c0 = blockIdx.x * 256 + w * 64;

    f32x4 acc[4] = {{0.f,0.f,0.f,0.f},{0.f,0.f,0.f,0.f},{0.f,0.f,0.f,0.f},{0.f,0.f,0.f,0.f}};
    const bf16* op = O2 + (size_t)(r0 + lo) * 512 + hi * 8;
    #pragma unroll 4
    for (int kb = 0; kb < 16; ++kb) {
        short8 a = ldb8(op + kb * 32);
        #pragma unroll
        for (int t = 0; t < 4; ++t) {
            short8 b = ldb8(W + (size_t)(c0 + t * 16 + lo) * 512 + kb * 32 + hi * 8);
            acc[t] = MFMA16(a, b, acc[t]);
        }
    }
    #pragma unroll
    for (int t = 0; t < 4; ++t) {
        const int col = c0 + t * 16 + lo;
        const float bcol = bias[col];
        #pragma unroll
        for (int r = 0; r < 4; ++r) {
            const int row = r0 + hi * 4 + r;
            Y[(size_t)row * 512 + col] = acc[t][r] + bcol;
        }
    }
}

// -------------------------------------------------------------------------
extern "C" void kernel_launch(void* const* d_in, const int* in_sizes, int n_in,
                              void* d_out, int out_size, void* d_ws, size_t ws_size,
                              hipStream_t stream)
{
    const float* x     = (const float*)d_in[0];
    const float* wqkv  = (const float*)d_in[1];
    const float* bqkv  = (const float*)d_in[2];
    const float* wproj = (const float*)d_in[3];
    const float* bproj = (const float*)d_in[4];
    const float* qvm   = (const float*)d_in[5];
    const float* kvm   = (const float*)d_in[6];
    const float* vvm   = (const float*)d_in[7];
    const float* avm   = (const float*)d_in[8];
    const int*   qac   = (const int*)d_in[9];
    const int*   kac   = (const int*)d_in[10];
    const int*   vac   = (const int*)d_in[11];
    const int*   aac   = (const int*)d_in[12];

    // workspace carve (~61 MB total)
    char* p = (char*)d_ws;
    bf16* Q2  = (bf16*)p; p += (size_t)32 * 1024 * 128 * 2;   // 8 MB  [bh][n][128]
    bf16* K2c = (bf16*)p; p += (size_t)32 * 1024 * 128 * 2;   // 8 MB  [bh][m][128]
    bf16* VsT = (bf16*)p; p += (size_t)32 * 64 * 1024 * 2;    // 4 MB  [bh][d][m]
    bf16* VaT = (bf16*)p; p += (size_t)32 * 64 * 1024 * 2;    // 4 MB
    bf16* P1  = (bf16*)p; p += (size_t)8 * 1024 * 1024 * 2;   // 16 MB [h][n][m] (per batch)
    bf16* P2  = (bf16*)p; p += (size_t)8 * 1024 * 1024 * 2;   // 16 MB
    bf16* O2  = (bf16*)p; p += (size_t)4096 * 512 * 2;        // 4 MB  [B*N][C]
    bf16* Wp  = (bf16*)p; p += (size_t)512 * 512 * 2;         // 0.5MB w_proj bf16

    k_cast<<<dim3(256), 256, 0, stream>>>(wproj, Wp, 512 * 512);
    k_qkv_f32<<<dim3(24, 64), 256, 0, stream>>>(x, wqkv, bqkv, qvm, kvm, vvm,
                                                qac, kac, vac, Q2, K2c, VsT, VaT);
    for (int b = 0; b < 4; ++b) {
        k_score<<<dim3(64, 8), 256, 0, stream>>>(Q2, K2c, avm, aac, P1, P2, b);
        k_pv<<<dim3(64, 8), 256, 0, stream>>>(P1, P2, VsT, VaT, O2, b);
    }
    k_proj<<<dim3(2, 256), 256, 0, stream>>>(O2, Wp, bproj, (float*)d_out);
}

// Round 3
// 535.321 us; speedup vs baseline: 1.3063x; 1.3063x over previous
//
#include <hip/hip_runtime.h>
#include <hip/hip_bf16.h>

typedef short short8 __attribute__((ext_vector_type(8)));
typedef float f32x4 __attribute__((ext_vector_type(4)));

using bf16 = __hip_bfloat16;

#define MFMA16(a, b, c) __builtin_amdgcn_mfma_f32_16x16x32_bf16((a), (b), (c), 0, 0, 0)

__device__ __forceinline__ short8 ldb8(const bf16* p) {
    return *reinterpret_cast<const short8*>(p);
}
// bf16 bits of a float that is exactly representable (small ints): truncate.
__device__ __forceinline__ unsigned int bfu(float f) {
    union { float f; unsigned int u; } x{f};
    return x.u >> 16;
}

// -------------------------------------------------------------------------
// Cast f32 -> bf16 (w_proj only).
// -------------------------------------------------------------------------
__global__ __launch_bounds__(256) void k_cast(const float* __restrict__ src,
                                              bf16* __restrict__ dst, int n)
{
    for (int i = blockIdx.x * 256 + threadIdx.x; i < n; i += gridDim.x * 256)
        dst[i] = __float2bfloat16(src[i]);
}

// -------------------------------------------------------------------------
// Kernel 1: QKV projection in f32 (IF discontinuity demands f32), 128x64 tile,
// 8x4 per thread, BK=16. Accumulation order per output = ascending k (bit-
// identical to round-2 pass). IF epilogue writes bf16 spike tensors:
//   Q2[bh,n,0:64]=qa0+sq  Q2[bh,n,64:128]=sq
//   K2[bh,m,0:64]=sk      K2[bh,m,64:128]=ka0
//   VsT[bh,d,n]=sv        VaT[bh,d,n]=va0   (transposed for PV B-frags)
// -------------------------------------------------------------------------
__global__ __launch_bounds__(256) void k_qkv_f32(
    const float* __restrict__ X, const float* __restrict__ W, const float* __restrict__ bq,
    const float* __restrict__ qvm, const float* __restrict__ kvm, const float* __restrict__ vvm,
    const int* __restrict__ qac, const int* __restrict__ kac, const int* __restrict__ vac,
    bf16* __restrict__ Q2, bf16* __restrict__ K2c, bf16* __restrict__ VsT, bf16* __restrict__ VaT)
{
    __shared__ float As[16][128];   // [k][row]
    __shared__ float Bs[16][68];    // [k][col] (+4 pad: write-conflict relief)
    const int tid = threadIdx.x;
    const int r0 = blockIdx.y * 128;          // rows (b*N+n)
    const int c0 = blockIdx.x * 64;           // cols (0..1535), head-aligned
    const int tm = (tid & 15) * 4;            // per-thread rows: tm..tm+3, tm+64..tm+67
    const int tn = (tid >> 4) * 4;            // per-thread cols: tn..tn+3

    // staging maps
    const int arow = tid >> 1, akh = (tid & 1) * 8;   // A: 128 rows x 16k, 8 floats/thread
    const int brow = tid >> 2, bkq = (tid & 3) * 4;   // B: 64 rows x 16k, 4 floats/thread

    float acc[8][4] = {};
    for (int kk = 0; kk < 512; kk += 16) {
        const float4 a0 = *reinterpret_cast<const float4*>(X + (size_t)(r0 + arow) * 512 + kk + akh);
        const float4 a1 = *reinterpret_cast<const float4*>(X + (size_t)(r0 + arow) * 512 + kk + akh + 4);
        const float4 b0 = *reinterpret_cast<const float4*>(W + (size_t)(c0 + brow) * 512 + kk + bkq);
        __syncthreads();
        As[akh + 0][arow] = a0.x; As[akh + 1][arow] = a0.y; As[akh + 2][arow] = a0.z; As[akh + 3][arow] = a0.w;
        As[akh + 4][arow] = a1.x; As[akh + 5][arow] = a1.y; As[akh + 6][arow] = a1.z; As[akh + 7][arow] = a1.w;
        Bs[bkq + 0][brow] = b0.x; Bs[bkq + 1][brow] = b0.y; Bs[bkq + 2][brow] = b0.z; Bs[bkq + 3][brow] = b0.w;
        __syncthreads();
        #pragma unroll
        for (int k = 0; k < 16; ++k) {
            const float4 av0 = *reinterpret_cast<const float4*>(&As[k][tm]);
            const float4 av1 = *reinterpret_cast<const float4*>(&As[k][tm + 64]);
            const float4 bv  = *reinterpret_cast<const float4*>(&Bs[k][tn]);
            const float ar[8] = {av0.x, av0.y, av0.z, av0.w, av1.x, av1.y, av1.z, av1.w};
            const float br[4] = {bv.x, bv.y, bv.z, bv.w};
            #pragma unroll
            for (int i = 0; i < 8; ++i)
                #pragma unroll
                for (int j = 0; j < 4; ++j)
                    acc[i][j] += ar[i] * br[j];
        }
    }

    const int sel = c0 >> 9;              // uniform per block
    const int h   = (c0 & 511) >> 6;      // uniform per block (64-col head-aligned tile)
    #pragma unroll
    for (int j = 0; j < 4; ++j) {
        const int col = c0 + tn + j;
        const int d = col & 63;
        const float bcol = bq[col];
        #pragma unroll
        for (int i = 0; i < 8; ++i) {
            const int row = r0 + ((i < 4) ? (tm + i) : (tm + 64 + i - 4));   // b*N+n
            const int b = row >> 10, n = row & 1023;
            const int bh = b * 8 + h;
            const size_t i4 = ((size_t)(bh * 1024 + n)) * 64 + d;
            const float val = acc[i][j] + bcol;
            float vm; int a0i;
            if (sel == 0)      { vm = qvm[i4]; a0i = qac[i4]; }
            else if (sel == 1) { vm = kvm[i4]; a0i = kac[i4]; }
            else               { vm = vvm[i4]; a0i = vac[i4]; }
            const float v_ = vm + val;
            int sp = ((v_ >= 1.0f) && (a0i < 7)) ? 1 : 0;
            if ((v_ < 0.0f) && (a0i > -8)) sp -= 1;
            if (sel == 0) {
                const size_t qi = ((size_t)(bh * 1024 + n)) * 128 + d;
                Q2[qi]      = __float2bfloat16((float)(a0i + sp));
                Q2[qi + 64] = __float2bfloat16((float)sp);
            } else if (sel == 1) {
                const size_t ki = ((size_t)(bh * 1024 + n)) * 128 + d;
                K2c[ki]      = __float2bfloat16((float)sp);
                K2c[ki + 64] = __float2bfloat16((float)a0i);
            } else {
                const size_t vi = ((size_t)(bh * 64 + d)) * 1024 + n;
                VsT[vi] = __float2bfloat16((float)sp);
                VaT[vi] = __float2bfloat16((float)a0i);
            }
        }
    }
}

// -------------------------------------------------------------------------
// Kernel 2 (fused, one dispatch): scores (MFMA, exact) -> softmax*7 (verbatim
// round-2 arithmetic, bit-identical) -> attn IF -> P1/P2 packed into the SAME
// 64 KB LDS (XOR-swizzled 8-elem blocks) -> PV double-GEMM (exact int) ->
// after-attn IF -> O2 [B,N,C].
// grid (64 n-tiles, 8 heads, 4 batches), 256 threads, 64 KB LDS, 2 blocks/CU.
// -------------------------------------------------------------------------
__global__ __launch_bounds__(256) void k_attn(
    const bf16* __restrict__ Q2, const bf16* __restrict__ K2c,
    const float* __restrict__ avm, const int* __restrict__ aac,
    const bf16* __restrict__ VsT, const bf16* __restrict__ VaT,
    bf16* __restrict__ O2)
{
    __shared__ float S[16 * 1024];        // 64 KB; reused as P1/P2 (bf16) later
    const int w = threadIdx.x >> 6, lane = threadIdx.x & 63;
    const int lo = lane & 15, hi = lane >> 4;
    const int h = blockIdx.y, bb = blockIdx.z;
    const int bh = bb * 8 + h;
    const int n0 = blockIdx.x * 16;

    // ---- Phase 1: scores -> S (bit-exact ints * 0.125) ----
    {
        const bf16* qb = Q2 + ((size_t)(bh * 1024 + n0 + lo)) * 128 + hi * 8;
        const short8 a0 = ldb8(qb), a1 = ldb8(qb + 32), a2 = ldb8(qb + 64), a3 = ldb8(qb + 96);
        for (int t = 0; t < 16; ++t) {
            const int c0 = w * 256 + t * 16;
            const bf16* kb = K2c + ((size_t)(bh * 1024 + c0 + lo)) * 128 + hi * 8;
            f32x4 acc = {0.f, 0.f, 0.f, 0.f};
            acc = MFMA16(a0, ldb8(kb),      acc);
            acc = MFMA16(a1, ldb8(kb + 32), acc);
            acc = MFMA16(a2, ldb8(kb + 64), acc);
            acc = MFMA16(a3, ldb8(kb + 96), acc);
            #pragma unroll
            for (int r = 0; r < 4; ++r)
                S[(hi * 4 + r) * 1024 + c0 + lo] = 0.125f * acc[r];
        }
    }
    __syncthreads();

    // ---- Phase 2: max / exp / sum — VERBATIM round-2 arithmetic ----
    const int row = threadIdx.x >> 4, l16 = threadIdx.x & 15;
    float* Sr = S + row * 1024;
    float mx = -3.0e38f;
    #pragma unroll 8
    for (int j = 0; j < 64; ++j) mx = fmaxf(mx, Sr[l16 + (j << 4)]);
    mx = fmaxf(mx, __shfl_xor(mx, 1));
    mx = fmaxf(mx, __shfl_xor(mx, 2));
    mx = fmaxf(mx, __shfl_xor(mx, 4));
    mx = fmaxf(mx, __shfl_xor(mx, 8));
    float sum = 0.f;
    #pragma unroll 8
    for (int j = 0; j < 64; ++j) {
        const int c = l16 + (j << 4);
        const float e = expf(Sr[c] - mx);
        Sr[c] = e;
        sum += e;
    }
    sum += __shfl_xor(sum, 1);
    sum += __shfl_xor(sum, 2);
    sum += __shfl_xor(sum, 4);
    sum += __shfl_xor(sum, 8);
    __syncthreads();

    // ---- Phase 3a: pull exp values into registers (blocked layout) ----
    // thread (row, q) owns 8-elem blocks kb = q + 16*j, j=0..7
    const int q = l16;
    float4 e4[16];
    #pragma unroll
    for (int j = 0; j < 8; ++j) {
        const int kb = q + 16 * j;
        e4[2 * j]     = *reinterpret_cast<const float4*>(&S[row * 1024 + kb * 8]);
        e4[2 * j + 1] = *reinterpret_cast<const float4*>(&S[row * 1024 + kb * 8 + 4]);
    }
    __syncthreads();   // all S reads done before P overwrites

    // ---- Phase 3b: attn IF, pack P1/P2 bf16 into LDS (XOR swizzle) ----
    // P1 = rows 0..15 x 1024 bf16 at S base; P2 at +16384 elements.
    bf16* P1b = (bf16*)S;
    bf16* P2b = P1b + 16 * 1024;
    const size_t gRow = ((size_t)bh * 1024 + (n0 + row)) * 1024;
    #pragma unroll
    for (int j = 0; j < 8; ++j) {
        const int kb = q + 16 * j;
        const int blk = kb ^ row;
        const float4 vm0 = *reinterpret_cast<const float4*>(avm + gRow + kb * 8);
        const float4 vm1 = *reinterpret_cast<const float4*>(avm + gRow + kb * 8 + 4);
        const int4  aa0 = *reinterpret_cast<const int4*>(aac + gRow + kb * 8);
        const int4  aa1 = *reinterpret_cast<const int4*>(aac + gRow + kb * 8 + 4);
        const float ev[8] = {e4[2*j].x, e4[2*j].y, e4[2*j].z, e4[2*j].w,
                             e4[2*j+1].x, e4[2*j+1].y, e4[2*j+1].z, e4[2*j+1].w};
        const float vmv[8] = {vm0.x, vm0.y, vm0.z, vm0.w, vm1.x, vm1.y, vm1.z, vm1.w};
        const int   aav[8] = {aa0.x, aa0.y, aa0.z, aa0.w, aa1.x, aa1.y, aa1.z, aa1.w};
        unsigned int p1u[8], p2u[8];
        #pragma unroll
        for (int i = 0; i < 8; ++i) {
            const float p7 = (ev[i] / sum) * 7.0f;          // same expr as round-2
            const float v_ = (vmv[i] + 0.2f) + p7;
            const int a0i = aav[i];
            int sp = ((v_ >= 1.0f) && (a0i < 7)) ? 1 : 0;
            if ((v_ < 0.0f) && (a0i > -8)) sp -= 1;
            p1u[i] = bfu((float)(a0i + sp));
            p2u[i] = bfu((float)sp);
        }
        uint4 w1, w2;
        w1.x = p1u[0] | (p1u[1] << 16); w1.y = p1u[2] | (p1u[3] << 16);
        w1.z = p1u[4] | (p1u[5] << 16); w1.w = p1u[6] | (p1u[7] << 16);
        w2.x = p2u[0] | (p2u[1] << 16); w2.y = p2u[2] | (p2u[3] << 16);
        w2.z = p2u[4] | (p2u[5] << 16); w2.w = p2u[6] | (p2u[7] << 16);
        *reinterpret_cast<uint4*>(P1b + row * 1024 + blk * 8) = w1;
        *reinterpret_cast<uint4*>(P2b + row * 1024 + blk * 8) = w2;
    }
    __syncthreads();

    // ---- Phase 4: PV (exact int MFMA), after-attn IF, write O2 ----
    {
        const int d0 = w * 16;
        const bf16* vs = VsT + ((size_t)(bh * 64 + d0 + lo)) * 1024 + hi * 8;
        const bf16* va = VaT + ((size_t)(bh * 64 + d0 + lo)) * 1024 + hi * 8;
        f32x4 acc = {0.f, 0.f, 0.f, 0.f};
        #pragma unroll 4
        for (int t = 0; t < 32; ++t) {
            const int blkA = (t * 4 + hi) ^ lo;
            const short8 a1 = ldb8(P1b + lo * 1024 + blkA * 8);
            const short8 a2 = ldb8(P2b + lo * 1024 + blkA * 8);
            acc = MFMA16(a1, ldb8(vs + t * 32), acc);
            acc = MFMA16(a2, ldb8(va + t * 32), acc);
        }
        #pragma unroll
        for (int r = 0; r < 4; ++r) {
            const int n = n0 + hi * 4 + r;
            const float o = acc[r];                 // exact integer
            const float o2 = (o >= 0.5f ? 1.f : 0.f) - (o < -0.5f ? 1.f : 0.f);
            O2[((size_t)(bb * 1024 + n)) * 512 + h * 64 + d0 + lo] = __float2bfloat16(o2);
        }
    }
}

// -------------------------------------------------------------------------
// Kernel 3: Y = O2 @ Wp^T + b_proj, f32 output (unchanged from round 2).
// -------------------------------------------------------------------------
__global__ __launch_bounds__(256) void k_proj(
    const bf16* __restrict__ O2, const bf16* __restrict__ W, const float* __restrict__ bias,
    float* __restrict__ Y)
{
    const int w = threadIdx.x >> 6, lane = threadIdx.x & 63;
    const int lo = lane & 15, hi = lane >> 4;
    const int r0 = blockIdx.y * 16;
    const int c0 = blockIdx.x * 256 + w * 64;

    f32x4 acc[4] = {{0.f,0.f,0.f,0.f},{0.f,0.f,0.f,0.f},{0.f,0.f,0.f,0.f},{0.f,0.f,0.f,0.f}};
    const bf16* op = O2 + (size_t)(r0 + lo) * 512 + hi * 8;
    #pragma unroll 4
    for (int kb = 0; kb < 16; ++kb) {
        short8 a = ldb8(op + kb * 32);
        #pragma unroll
        for (int t = 0; t < 4; ++t) {
            short8 b = ldb8(W + (size_t)(c0 + t * 16 + lo) * 512 + kb * 32 + hi * 8);
            acc[t] = MFMA16(a, b, acc[t]);
        }
    }
    #pragma unroll
    for (int t = 0; t < 4; ++t) {
        const int col = c0 + t * 16 + lo;
        const float bcol = bias[col];
        #pragma unroll
        for (int r = 0; r < 4; ++r) {
            const int row = r0 + hi * 4 + r;
            Y[(size_t)row * 512 + col] = acc[t][r] + bcol;
        }
    }
}

// -------------------------------------------------------------------------
extern "C" void kernel_launch(void* const* d_in, const int* in_sizes, int n_in,
                              void* d_out, int out_size, void* d_ws, size_t ws_size,
                              hipStream_t stream)
{
    const float* x     = (const float*)d_in[0];
    const float* wqkv  = (const float*)d_in[1];
    const float* bqkv  = (const float*)d_in[2];
    const float* wproj = (const float*)d_in[3];
    const float* bproj = (const float*)d_in[4];
    const float* qvm   = (const float*)d_in[5];
    const float* kvm   = (const float*)d_in[6];
    const float* vvm   = (const float*)d_in[7];
    const float* avm   = (const float*)d_in[8];
    const int*   qac   = (const int*)d_in[9];
    const int*   kac   = (const int*)d_in[10];
    const int*   vac   = (const int*)d_in[11];
    const int*   aac   = (const int*)d_in[12];

    // workspace carve (~29 MB)
    char* p = (char*)d_ws;
    bf16* Q2  = (bf16*)p; p += (size_t)32 * 1024 * 128 * 2;   // 8 MB  [bh][n][128]
    bf16* K2c = (bf16*)p; p += (size_t)32 * 1024 * 128 * 2;   // 8 MB  [bh][m][128]
    bf16* VsT = (bf16*)p; p += (size_t)32 * 64 * 1024 * 2;    // 4 MB  [bh][d][m]
    bf16* VaT = (bf16*)p; p += (size_t)32 * 64 * 1024 * 2;    // 4 MB
    bf16* O2  = (bf16*)p; p += (size_t)4096 * 512 * 2;        // 4 MB  [B*N][C]
    bf16* Wp  = (bf16*)p; p += (size_t)512 * 512 * 2;         // 0.5MB w_proj bf16

    k_cast<<<dim3(256), 256, 0, stream>>>(wproj, Wp, 512 * 512);
    k_qkv_f32<<<dim3(24, 32), 256, 0, stream>>>(x, wqkv, bqkv, qvm, kvm, vvm,
                                                qac, kac, vac, Q2, K2c, VsT, VaT);
    k_attn<<<dim3(64, 8, 4), 256, 0, stream>>>(Q2, K2c, avm, aac, VsT, VaT, O2);
    k_proj<<<dim3(2, 256), 256, 0, stream>>>(O2, Wp, bproj, (float*)d_out);
}

// Round 4
// 529.425 us; speedup vs baseline: 1.3209x; 1.0111x over previous
//
#include <hip/hip_runtime.h>
#include <hip/hip_bf16.h>

typedef short short8 __attribute__((ext_vector_type(8)));
typedef float f32x4 __attribute__((ext_vector_type(4)));

using bf16 = __hip_bfloat16;

#define MFMA16(a, b, c) __builtin_amdgcn_mfma_f32_16x16x32_bf16((a), (b), (c), 0, 0, 0)

__device__ __forceinline__ short8 ldb8(const bf16* p) {
    return *reinterpret_cast<const short8*>(p);
}
__device__ __forceinline__ unsigned int bfu(float f) {   // exact small ints -> bf16 bits
    union { float f; unsigned int u; } x{f};
    return x.u >> 16;
}

// -------------------------------------------------------------------------
__global__ __launch_bounds__(256) void k_cast(const float* __restrict__ src,
                                              bf16* __restrict__ dst, int n)
{
    for (int i = blockIdx.x * 256 + threadIdx.x; i < n; i += gridDim.x * 256)
        dst[i] = __float2bfloat16(src[i]);
}

// -------------------------------------------------------------------------
// Kernel 1: QKV projection f32, 64x128 tile, 4x8/thread, BK=16.
// Per-output accumulation ascending k => bit-identical to round-2/3 pass.
// -------------------------------------------------------------------------
__global__ __launch_bounds__(256, 3) void k_qkv_f32(
    const float* __restrict__ X, const float* __restrict__ W, const float* __restrict__ bq,
    const float* __restrict__ qvm, const float* __restrict__ kvm, const float* __restrict__ vvm,
    const int* __restrict__ qac, const int* __restrict__ kac, const int* __restrict__ vac,
    bf16* __restrict__ Q2, bf16* __restrict__ K2c, bf16* __restrict__ VsT, bf16* __restrict__ VaT)
{
    __shared__ float As[16][64];
    __shared__ float Bs[16][128];
    const int tid = threadIdx.x;
    const int r0 = blockIdx.y * 64;            // rows (b*N+n)
    const int c0 = blockIdx.x * 128;           // cols (0..1535)
    const int tm = (tid & 15) * 4;             // 4 rows
    const int tn = (tid >> 4) * 8;             // 8 cols
    const int arow = tid >> 2, ak = (tid & 3) * 4;
    const int brow = tid >> 1, bk = (tid & 1) * 8;

    float acc[4][8] = {};
    for (int kk = 0; kk < 512; kk += 16) {
        const float4 a4 = *reinterpret_cast<const float4*>(X + (size_t)(r0 + arow) * 512 + kk + ak);
        const float4 w0 = *reinterpret_cast<const float4*>(W + (size_t)(c0 + brow) * 512 + kk + bk);
        const float4 w1 = *reinterpret_cast<const float4*>(W + (size_t)(c0 + brow) * 512 + kk + bk + 4);
        __syncthreads();
        As[ak + 0][arow] = a4.x; As[ak + 1][arow] = a4.y; As[ak + 2][arow] = a4.z; As[ak + 3][arow] = a4.w;
        Bs[bk + 0][brow] = w0.x; Bs[bk + 1][brow] = w0.y; Bs[bk + 2][brow] = w0.z; Bs[bk + 3][brow] = w0.w;
        Bs[bk + 4][brow] = w1.x; Bs[bk + 5][brow] = w1.y; Bs[bk + 6][brow] = w1.z; Bs[bk + 7][brow] = w1.w;
        __syncthreads();
        #pragma unroll
        for (int k = 0; k < 16; ++k) {
            const float4 av = *reinterpret_cast<const float4*>(&As[k][tm]);
            const float4 bv0 = *reinterpret_cast<const float4*>(&Bs[k][tn]);
            const float4 bv1 = *reinterpret_cast<const float4*>(&Bs[k][tn + 4]);
            const float ar[4] = {av.x, av.y, av.z, av.w};
            const float br[8] = {bv0.x, bv0.y, bv0.z, bv0.w, bv1.x, bv1.y, bv1.z, bv1.w};
            #pragma unroll
            for (int i = 0; i < 4; ++i)
                #pragma unroll
                for (int j = 0; j < 8; ++j)
                    acc[i][j] += ar[i] * br[j];
        }
    }

    const int sel = c0 >> 9;                   // block-uniform (128-col tiles are 512-aligned groups)
    const int h   = ((c0 + tn) & 511) >> 6;    // thread-uniform (8-col group within one head)
    const int d0  = (c0 + tn) & 63;
    const float4 bb0 = *reinterpret_cast<const float4*>(bq + c0 + tn);
    const float4 bb1 = *reinterpret_cast<const float4*>(bq + c0 + tn + 4);
    const float bcol[8] = {bb0.x, bb0.y, bb0.z, bb0.w, bb1.x, bb1.y, bb1.z, bb1.w};

    // load vmem/acc for all 4 rows (8 cols contiguous at d0)
    const float* VM = (sel == 0) ? qvm : (sel == 1) ? kvm : vvm;
    const int*   AC = (sel == 0) ? qac : (sel == 1) ? kac : vac;
    float vmv[4][8]; int acv[4][8]; int bhn[4];
    #pragma unroll
    for (int i = 0; i < 4; ++i) {
        const int r = r0 + tm + i;
        const int b = r >> 10, n = r & 1023;
        const int bh = b * 8 + h;
        bhn[i] = bh * 1024 + n;
        const size_t i4 = (size_t)bhn[i] * 64 + d0;
        const float4 v0 = *reinterpret_cast<const float4*>(VM + i4);
        const float4 v1 = *reinterpret_cast<const float4*>(VM + i4 + 4);
        const int4  c0i = *reinterpret_cast<const int4*>(AC + i4);
        const int4  c1i = *reinterpret_cast<const int4*>(AC + i4 + 4);
        vmv[i][0]=v0.x; vmv[i][1]=v0.y; vmv[i][2]=v0.z; vmv[i][3]=v0.w;
        vmv[i][4]=v1.x; vmv[i][5]=v1.y; vmv[i][6]=v1.z; vmv[i][7]=v1.w;
        acv[i][0]=c0i.x; acv[i][1]=c0i.y; acv[i][2]=c0i.z; acv[i][3]=c0i.w;
        acv[i][4]=c1i.x; acv[i][5]=c1i.y; acv[i][6]=c1i.z; acv[i][7]=c1i.w;
    }

    int spm[4][8];
    #pragma unroll
    for (int i = 0; i < 4; ++i)
        #pragma unroll
        for (int j = 0; j < 8; ++j) {
            const float v_ = vmv[i][j] + (acc[i][j] + bcol[j]);
            // acc0 in [0,7] => neg gate's acc0 > -8 always true
            int sp = ((v_ >= 1.0f) && (acv[i][j] < 7)) ? 1 : 0;
            if (v_ < 0.0f) sp -= 1;
            spm[i][j] = sp;
        }

    if (sel == 2) {   // VsT/VaT transposed: pack 4 consecutive n per column
        #pragma unroll
        for (int j = 0; j < 8; ++j) {
            const int nb = (r0 & 1023) + tm;
            uint2 us, ua;
            us.x = bfu((float)spm[0][j]) | (bfu((float)spm[1][j]) << 16);
            us.y = bfu((float)spm[2][j]) | (bfu((float)spm[3][j]) << 16);
            ua.x = bfu((float)acv[0][j]) | (bfu((float)acv[1][j]) << 16);
            ua.y = bfu((float)acv[2][j]) | (bfu((float)acv[3][j]) << 16);
            const size_t vi = ((size_t)((bhn[0] >> 10) * 64 + d0 + j)) * 1024 + nb;
            *reinterpret_cast<uint2*>(VsT + vi) = us;
            *reinterpret_cast<uint2*>(VaT + vi) = ua;
        }
    } else {
        #pragma unroll
        for (int i = 0; i < 4; ++i) {
            uint4 p0, p1;
            unsigned u0[8], u1[8];
            #pragma unroll
            for (int j = 0; j < 8; ++j) {
                if (sel == 0) { u0[j] = bfu((float)(acv[i][j] + spm[i][j])); u1[j] = bfu((float)spm[i][j]); }
                else          { u0[j] = bfu((float)spm[i][j]);               u1[j] = bfu((float)acv[i][j]); }
            }
            p0.x = u0[0]|(u0[1]<<16); p0.y = u0[2]|(u0[3]<<16); p0.z = u0[4]|(u0[5]<<16); p0.w = u0[6]|(u0[7]<<16);
            p1.x = u1[0]|(u1[1]<<16); p1.y = u1[2]|(u1[3]<<16); p1.z = u1[4]|(u1[5]<<16); p1.w = u1[6]|(u1[7]<<16);
            bf16* base = ((sel == 0) ? Q2 : K2c) + (size_t)bhn[i] * 128 + d0;
            *reinterpret_cast<uint4*>(base)      = p0;
            *reinterpret_cast<uint4*>(base + 64) = p1;
        }
    }
}

// -------------------------------------------------------------------------
// Kernel 2 (fused): scores MFMA -> softmax (verbatim arithmetic) -> attn IF
// -> P pack (LDS overlay, two half-passes) -> PV MFMA -> after-IF -> O2.
// avm/aac prefetched to registers right after phase 1 (latency overlap).
// S layout: two 32KB halves, sidx(row,c) = ((c>>9)<<13) + row*512 + (c&511).
// -------------------------------------------------------------------------
__global__ __launch_bounds__(256, 2) void k_attn(
    const bf16* __restrict__ Q2, const bf16* __restrict__ K2c,
    const float* __restrict__ avm, const int* __restrict__ aac,
    const bf16* __restrict__ VsT, const bf16* __restrict__ VaT,
    bf16* __restrict__ O2)
{
    __shared__ float S[16 * 1024];
    char* const Sc = (char*)S;
    const int w = threadIdx.x >> 6, lane = threadIdx.x & 63;
    const int lo = lane & 15, hi = lane >> 4;
    const int h = blockIdx.y, bb = blockIdx.z;
    const int bh = bb * 8 + h;
    const int n0 = blockIdx.x * 16;

    // ---- Phase 1: scores -> S (exact ints * 0.125), K2c frags pipelined ----
    {
        const bf16* qb = Q2 + ((size_t)(bh * 1024 + n0 + lo)) * 128 + hi * 8;
        const short8 a0 = ldb8(qb), a1 = ldb8(qb + 32), a2 = ldb8(qb + 64), a3 = ldb8(qb + 96);
        const bf16* kbp = K2c + ((size_t)(bh * 1024 + w * 256 + lo)) * 128 + hi * 8;
        short8 b0 = ldb8(kbp), b1 = ldb8(kbp + 32), b2 = ldb8(kbp + 64), b3 = ldb8(kbp + 96);
        for (int t = 0; t < 16; ++t) {
            const short8 c0f = b0, c1f = b1, c2f = b2, c3f = b3;
            if (t < 15) {
                kbp += 16 * 128;
                b0 = ldb8(kbp); b1 = ldb8(kbp + 32); b2 = ldb8(kbp + 64); b3 = ldb8(kbp + 96);
            }
            f32x4 acc = {0.f, 0.f, 0.f, 0.f};
            acc = MFMA16(a0, c0f, acc);
            acc = MFMA16(a1, c1f, acc);
            acc = MFMA16(a2, c2f, acc);
            acc = MFMA16(a3, c3f, acc);
            const int cc = w * 256 + t * 16 + lo;
            const int sbase = ((cc >> 9) << 13) + (cc & 511);
            #pragma unroll
            for (int r = 0; r < 4; ++r)
                S[sbase + (hi * 4 + r) * 512] = 0.125f * acc[r];
        }
    }

    // ---- Prefetch avm/aac for this thread's phase-3 columns (burst; hidden
    //      behind softmax). thread (row,q) owns 8-col blocks kb = q+16j. ----
    const int row = threadIdx.x >> 4, q = threadIdx.x & 15;
    const size_t gRow = ((size_t)bh * 1024 + (n0 + row)) * 1024;
    float4 vmv[16]; int4 acv[16];
    #pragma unroll
    for (int j = 0; j < 8; ++j) {
        const int cb = (q + 16 * j) * 8;
        vmv[2*j]   = *reinterpret_cast<const float4*>(avm + gRow + cb);
        vmv[2*j+1] = *reinterpret_cast<const float4*>(avm + gRow + cb + 4);
        acv[2*j]   = *reinterpret_cast<const int4*>(aac + gRow + cb);
        acv[2*j+1] = *reinterpret_cast<const int4*>(aac + gRow + cb + 4);
    }
    __syncthreads();

    // ---- Phase 2: max / exp / sum — verbatim round-2/3 arithmetic ----
    float mx = -3.0e38f;
    #pragma unroll 8
    for (int j = 0; j < 64; ++j) {
        const int c = q + (j << 4);
        mx = fmaxf(mx, S[((c >> 9) << 13) + row * 512 + (c & 511)]);
    }
    mx = fmaxf(mx, __shfl_xor(mx, 1));
    mx = fmaxf(mx, __shfl_xor(mx, 2));
    mx = fmaxf(mx, __shfl_xor(mx, 4));
    mx = fmaxf(mx, __shfl_xor(mx, 8));
    float sum = 0.f;
    #pragma unroll 8
    for (int j = 0; j < 64; ++j) {
        const int c = q + (j << 4);
        const int si = ((c >> 9) << 13) + row * 512 + (c & 511);
        const float e = expf(S[si] - mx);
        S[si] = e;
        sum += e;
    }
    sum += __shfl_xor(sum, 1);
    sum += __shfl_xor(sum, 2);
    sum += __shfl_xor(sum, 4);
    sum += __shfl_xor(sum, 8);
    __syncthreads();   // all exp writes visible

    // ---- Phase 3, pass A (cols 0..511 = H0): read e, then overwrite H0 w/ P ----
    float4 eA[8];
    #pragma unroll
    for (int j = 0; j < 4; ++j) {
        const int cb = (q + 16 * j) * 8;           // < 512
        eA[2*j]   = *reinterpret_cast<const float4*>(&S[row * 512 + cb]);
        eA[2*j+1] = *reinterpret_cast<const float4*>(&S[row * 512 + cb + 4]);
    }
    __syncthreads();   // all H0 e-reads done before H0 is overwritten with P

    #pragma unroll
    for (int j = 0; j < 4; ++j) {
        const int kb = q + 16 * j;                 // < 64 -> half 0
        const float ev[8] = {eA[2*j].x, eA[2*j].y, eA[2*j].z, eA[2*j].w,
                             eA[2*j+1].x, eA[2*j+1].y, eA[2*j+1].z, eA[2*j+1].w};
        const float vmr[8] = {vmv[2*j].x, vmv[2*j].y, vmv[2*j].z, vmv[2*j].w,
                              vmv[2*j+1].x, vmv[2*j+1].y, vmv[2*j+1].z, vmv[2*j+1].w};
        const int aar[8] = {acv[2*j].x, acv[2*j].y, acv[2*j].z, acv[2*j].w,
                            acv[2*j+1].x, acv[2*j+1].y, acv[2*j+1].z, acv[2*j+1].w};
        unsigned p1u[8], p2u[8];
        #pragma unroll
        for (int i = 0; i < 8; ++i) {
            const float p7 = (ev[i] / sum) * 7.0f;
            const float v_ = (vmr[i] + 0.2f) + p7;   // v_ > 0 always (avm>=0, p7>0)
            const int a0i = aar[i];                  // in [0,7] -> neg gate never fires
            const int sp = ((v_ >= 1.0f) && (a0i < 7)) ? 1 : 0;
            p1u[i] = bfu((float)(a0i + sp));
            p2u[i] = bfu((float)sp);
        }
        uint4 w1, w2;
        w1.x = p1u[0]|(p1u[1]<<16); w1.y = p1u[2]|(p1u[3]<<16); w1.z = p1u[4]|(p1u[5]<<16); w1.w = p1u[6]|(p1u[7]<<16);
        w2.x = p2u[0]|(p2u[1]<<16); w2.y = p2u[2]|(p2u[3]<<16); w2.z = p2u[4]|(p2u[5]<<16); w2.w = p2u[6]|(p2u[7]<<16);
        char* pb = Sc + row * 2048 + ((kb ^ row) & 63) * 16;   // half 0
        *reinterpret_cast<uint4*>(pb)        = w1;
        *reinterpret_cast<uint4*>(pb + 1024) = w2;
    }

    // ---- Phase 3, pass B (cols 512..1023 = H1, untouched by pass A) ----
    float4 eB[8];
    #pragma unroll
    for (int j = 4; j < 8; ++j) {
        const int cb = (q + 16 * j) * 8;           // >= 512
        eB[2*(j-4)]   = *reinterpret_cast<const float4*>(&S[8192 + row * 512 + (cb - 512)]);
        eB[2*(j-4)+1] = *reinterpret_cast<const float4*>(&S[8192 + row * 512 + (cb - 512) + 4]);
    }
    __syncthreads();   // all H1 e-reads done before H1 is overwritten with P

    #pragma unroll
    for (int j = 4; j < 8; ++j) {
        const int kb = q + 16 * j;                 // >= 64 -> half 1
        const int jj = j - 4;
        const float ev[8] = {eB[2*jj].x, eB[2*jj].y, eB[2*jj].z, eB[2*jj].w,
                             eB[2*jj+1].x, eB[2*jj+1].y, eB[2*jj+1].z, eB[2*jj+1].w};
        const float vmr[8] = {vmv[2*j].x, vmv[2*j].y, vmv[2*j].z, vmv[2*j].w,
                              vmv[2*j+1].x, vmv[2*j+1].y, vmv[2*j+1].z, vmv[2*j+1].w};
        const int aar[8] = {acv[2*j].x, acv[2*j].y, acv[2*j].z, acv[2*j].w,
                            acv[2*j+1].x, acv[2*j+1].y, acv[2*j+1].z, acv[2*j+1].w};
        unsigned p1u[8], p2u[8];
        #pragma unroll
        for (int i = 0; i < 8; ++i) {
            const float p7 = (ev[i] / sum) * 7.0f;
            const float v_ = (vmr[i] + 0.2f) + p7;
            const int a0i = aar[i];
            const int sp = ((v_ >= 1.0f) && (a0i < 7)) ? 1 : 0;
            p1u[i] = bfu((float)(a0i + sp));
            p2u[i] = bfu((float)sp);
        }
        uint4 w1, w2;
        w1.x = p1u[0]|(p1u[1]<<16); w1.y = p1u[2]|(p1u[3]<<16); w1.z = p1u[4]|(p1u[5]<<16); w1.w = p1u[6]|(p1u[7]<<16);
        w2.x = p2u[0]|(p2u[1]<<16); w2.y = p2u[2]|(p2u[3]<<16); w2.z = p2u[4]|(p2u[5]<<16); w2.w = p2u[6]|(p2u[7]<<16);
        char* pb = Sc + 32768 + row * 2048 + ((kb & 63) ^ row) * 16;   // half 1
        *reinterpret_cast<uint4*>(pb)        = w1;
        *reinterpret_cast<uint4*>(pb + 1024) = w2;
    }
    __syncthreads();   // P fully written

    // ---- Phase 4: PV (exact int MFMA), after-attn IF, write O2 ----
    {
        const int d0 = w * 16;
        const bf16* vs = VsT + ((size_t)(bh * 64 + d0 + lo)) * 1024 + hi * 8;
        const bf16* va = VaT + ((size_t)(bh * 64 + d0 + lo)) * 1024 + hi * 8;
        short8 nvs = ldb8(vs), nva = ldb8(va);
        f32x4 acc = {0.f, 0.f, 0.f, 0.f};
        for (int tt = 0; tt < 32; ++tt) {
            const short8 cvs = nvs, cva = nva;
            if (tt < 31) { nvs = ldb8(vs + (tt + 1) * 32); nva = ldb8(va + (tt + 1) * 32); }
            const int kb_lin = tt * 4 + hi;
            const char* pb = Sc + (kb_lin >> 6) * 32768 + lo * 2048 + (((kb_lin & 63) ^ lo)) * 16;
            const short8 a1 = *reinterpret_cast<const short8*>(pb);
            const short8 a2 = *reinterpret_cast<const short8*>(pb + 1024);
            acc = MFMA16(a1, cvs, acc);
            acc = MFMA16(a2, cva, acc);
        }
        #pragma unroll
        for (int r = 0; r < 4; ++r) {
            const int n = n0 + hi * 4 + r;
            const float o = acc[r];                 // exact integer
            const float o2 = (o >= 0.5f ? 1.f : 0.f) - (o < -0.5f ? 1.f : 0.f);
            O2[((size_t)(bb * 1024 + n)) * 512 + h * 64 + d0 + lo] = __float2bfloat16(o2);
        }
    }
}

// -------------------------------------------------------------------------
// Kernel 3: Y = O2 @ Wp^T + b_proj, f32 out (unchanged).
// -------------------------------------------------------------------------
__global__ __launch_bounds__(256) void k_proj(
    const bf16* __restrict__ O2, const bf16* __restrict__ W, const float* __restrict__ bias,
    float* __restrict__ Y)
{
    const int w = threadIdx.x >> 6, lane = threadIdx.x & 63;
    const int lo = lane & 15, hi = lane >> 4;
    const int r0 = blockIdx.y * 16;
    const int c0 = blockIdx.x * 256 + w * 64;

    f32x4 acc[4] = {{0.f,0.f,0.f,0.f},{0.f,0.f,0.f,0.f},{0.f,0.f,0.f,0.f},{0.f,0.f,0.f,0.f}};
    const bf16* op = O2 + (size_t)(r0 + lo) * 512 + hi * 8;
    #pragma unroll 4
    for (int kb = 0; kb < 16; ++kb) {
        short8 a = ldb8(op + kb * 32);
        #pragma unroll
        for (int t = 0; t < 4; ++t) {
            short8 b = ldb8(W + (size_t)(c0 + t * 16 + lo) * 512 + kb * 32 + hi * 8);
            acc[t] = MFMA16(a, b, acc[t]);
        }
    }
    #pragma unroll
    for (int t = 0; t < 4; ++t) {
        const int col = c0 + t * 16 + lo;
        const float bcol = bias[col];
        #pragma unroll
        for (int r = 0; r < 4; ++r) {
            const int rr = r0 + hi * 4 + r;
            Y[(size_t)rr * 512 + col] = acc[t][r] + bcol;
        }
    }
}

// -------------------------------------------------------------------------
extern "C" void kernel_launch(void* const* d_in, const int* in_sizes, int n_in,
                              void* d_out, int out_size, void* d_ws, size_t ws_size,
                              hipStream_t stream)
{
    const float* x     = (const float*)d_in[0];
    const float* wqkv  = (const float*)d_in[1];
    const float* bqkv  = (const float*)d_in[2];
    const float* wproj = (const float*)d_in[3];
    const float* bproj = (const float*)d_in[4];
    const float* qvm   = (const float*)d_in[5];
    const float* kvm   = (const float*)d_in[6];
    const float* vvm   = (const float*)d_in[7];
    const float* avm   = (const float*)d_in[8];
    const int*   qac   = (const int*)d_in[9];
    const int*   kac   = (const int*)d_in[10];
    const int*   vac   = (const int*)d_in[11];
    const int*   aac   = (const int*)d_in[12];

    char* p = (char*)d_ws;
    bf16* Q2  = (bf16*)p; p += (size_t)32 * 1024 * 128 * 2;   // 8 MB  [bh][n][128]
    bf16* K2c = (bf16*)p; p += (size_t)32 * 1024 * 128 * 2;   // 8 MB  [bh][m][128]
    bf16* VsT = (bf16*)p; p += (size_t)32 * 64 * 1024 * 2;    // 4 MB  [bh][d][m]
    bf16* VaT = (bf16*)p; p += (size_t)32 * 64 * 1024 * 2;    // 4 MB
    bf16* O2  = (bf16*)p; p += (size_t)4096 * 512 * 2;        // 4 MB  [B*N][C]
    bf16* Wp  = (bf16*)p; p += (size_t)512 * 512 * 2;         // 0.5MB w_proj bf16

    k_cast<<<dim3(256), 256, 0, stream>>>(wproj, Wp, 512 * 512);
    k_qkv_f32<<<dim3(12, 64), 256, 0, stream>>>(x, wqkv, bqkv, qvm, kvm, vvm,
                                                qac, kac, vac, Q2, K2c, VsT, VaT);
    k_attn<<<dim3(64, 8, 4), 256, 0, stream>>>(Q2, K2c, avm, aac, VsT, VaT, O2);
    k_proj<<<dim3(2, 256), 256, 0, stream>>>(O2, Wp, bproj, (float*)d_out);
}